// Round 10
// baseline (202.484 us; speedup 1.0000x reference)
//
#include <hip/hip_runtime.h>
#include <stdint.h>

typedef __attribute__((ext_vector_type(8))) short short8;
typedef __attribute__((ext_vector_type(4))) float floatx4;

#define B_SZ 2
#define T_SZ 2048
#define NH   16
#define HD   64
#define C_SZ 1024
#define M_SZ (B_SZ * T_SZ)   // 4096 tokens

// packed fp32x2 -> bf16x2 (RNE), gfx950 hardware instruction
static __device__ __forceinline__ unsigned int cvt2(float a, float b) {
    unsigned int r;
    asm("v_cvt_pk_bf16_f32 %0, %1, %2" : "=v"(r) : "v"(a), "v"(b));
    return r;
}

// async global->LDS, 16B per lane; LDS dest = wave-uniform base + lane*16
static __device__ __forceinline__ void gload_lds16(const void* g, void* l) {
    __builtin_amdgcn_global_load_lds(
        (const __attribute__((address_space(1))) void*)g,
        (__attribute__((address_space(3))) void*)l, 16, 0, 0);
}

// ---------------------------------------------------------------------------
// fp32 -> bf16 pre-convert (memory-bound): y=0 -> x, y=1..4 -> W's
// ---------------------------------------------------------------------------
__global__ __launch_bounds__(256)
void cvtk(const float* __restrict__ x,
          const float* __restrict__ w0, const float* __restrict__ w1,
          const float* __restrict__ w2, const float* __restrict__ w3,
          unsigned short* __restrict__ xb, unsigned short* __restrict__ wb)
{
    const float* src; unsigned short* dst; int n4;
    const int y = blockIdx.y;
    if (y == 0) { src = x; dst = xb; n4 = (M_SZ * C_SZ) / 4; }
    else {
        src = (y == 1 ? w0 : y == 2 ? w1 : y == 3 ? w2 : w3);
        dst = wb + (size_t)(y - 1) * C_SZ * C_SZ;
        n4 = (C_SZ * C_SZ) / 4;
    }
    for (int i = blockIdx.x * 256 + threadIdx.x; i < n4; i += gridDim.x * 256) {
        float4 f = *(const float4*)&src[(size_t)i * 4];
        uint2 u;
        u.x = cvt2(f.x, f.y);
        u.y = cvt2(f.z, f.w);
        *(uint2*)&dst[(size_t)i * 4] = u;
    }
}

// ---------------------------------------------------------------------------
// NT GEMM, all-bf16: C[m,n] = sum_k A[m,k]*W[n,k]  (M=4096, N=K=1024)
// 128x128 tile, BK=32 DOUBLE-BUFFERED (one barrier/iter; prefetch of tile
// kt+1 issued right after the barrier, its vmcnt drain lands at the NEXT
// barrier -> staging latency off the critical path; same structure that
// fixed attn in R8). 2x2 waves, 4x4 16x16x32 MFMAs per iter.
// LDS unpadded, XOR-swizzled: slot s of row r holds global chunk
// s^((r>>1)&3); frag reads hit each (parity, slot) combo twice -> 2-way.
// MODE 0 (QKV): Wp = Wb + z*C*C; fused epilogues:
//   z=0/1: RoPE + RMSNorm (+0.125*log2e for q) -> qh/kh in PERMUTED-D layout
//          (pos l16*4+j holds d = j*16+l16 — QK-dot invariant, both sides).
//   z=2: transpose -> vt (B,H,D,T), true d.
// MODE 1 (out-proj): writes fp32 (B,T,C) to Cf.
// ---------------------------------------------------------------------------
template <int MODE>
__global__ __launch_bounds__(256)
void gemm_nt(const unsigned short* __restrict__ A,
             const unsigned short* __restrict__ Wb,
             const float* __restrict__ cosp,
             const float* __restrict__ sinp,
             unsigned short* __restrict__ qh,
             unsigned short* __restrict__ kh,
             unsigned short* __restrict__ vt,
             float* __restrict__ Cf)
{
    // two 128x32 bf16 buffers per matrix: 4 x 8192 B = 32 KB
    __shared__ __align__(16) unsigned short As[2][128 * 32];
    __shared__ __align__(16) unsigned short Bs[2][128 * 32];

    const int tid  = threadIdx.x;
    const int wave = tid >> 6, lane = tid & 63;
    const int wm = wave >> 1, wn = wave & 1;
    const int quad = lane >> 4, l16 = lane & 15;
    const int mb = blockIdx.x * 128, nb = blockIdx.y * 128;
    const int z  = blockIdx.z;

    const unsigned short* Wp = (MODE == 0) ? (Wb + (size_t)z * C_SZ * C_SZ) : Wb;

    floatx4 acc[4][4] = {};

    // staging geometry: wave w, round j covers rows j*64 + w*16 .. +15;
    // lane covers (row = +lane>>2, slot = lane&3); source col chunk
    // = (slot ^ ((row>>1)&3)) * 8
    const int sr_off = (lane >> 2);            // 0..15 within chunk
    const int sslot  = lane & 3;

    // prologue: stage tile 0 into buf 0
    #pragma unroll
    for (int j = 0; j < 2; ++j) {
        int rb = j * 64 + wave * 16;
        int r  = rb + sr_off;
        int col = (sslot ^ ((r >> 1) & 3)) * 8;
        gload_lds16(&A[(size_t)(mb + r) * C_SZ + col], &As[0][rb * 32]);
        gload_lds16(&Wp[(size_t)(nb + r) * C_SZ + col], &Bs[0][rb * 32]);
    }

    for (int kt = 0; kt < 32; ++kt) {
        const int cur = kt & 1;

        __syncthreads();   // buf[cur] staged (vmcnt drained); buf[cur^1] free

        // prefetch next tile into the other buffer (wraps on last iter)
        {
            const int k0 = ((kt + 1) & 31) * 32;
            #pragma unroll
            for (int j = 0; j < 2; ++j) {
                int rb = j * 64 + wave * 16;
                int r  = rb + sr_off;
                int col = k0 + (sslot ^ ((r >> 1) & 3)) * 8;
                gload_lds16(&A[(size_t)(mb + r) * C_SZ + col], &As[cur ^ 1][rb * 32]);
                gload_lds16(&Wp[(size_t)(nb + r) * C_SZ + col], &Bs[cur ^ 1][rb * 32]);
            }
        }

        short8 af[4], bfr[4];
        #pragma unroll
        for (int mt = 0; mt < 4; ++mt) {
            int r = wm * 64 + mt * 16 + l16;
            af[mt] = *(const short8*)&As[cur][r * 32 + ((quad ^ ((r >> 1) & 3)) * 8)];
        }
        #pragma unroll
        for (int nt = 0; nt < 4; ++nt) {
            int r = wn * 64 + nt * 16 + l16;
            bfr[nt] = *(const short8*)&Bs[cur][r * 32 + ((quad ^ ((r >> 1) & 3)) * 8)];
        }
        #pragma unroll
        for (int mt = 0; mt < 4; ++mt)
            #pragma unroll
            for (int nt = 0; nt < 4; ++nt)
                acc[mt][nt] = __builtin_amdgcn_mfma_f32_16x16x32_bf16(
                    af[mt], bfr[nt], acc[mt][nt], 0, 0, 0);
    }

    if (MODE == 1) {
        #pragma unroll
        for (int mt = 0; mt < 4; ++mt)
            #pragma unroll
            for (int nt = 0; nt < 4; ++nt)
                #pragma unroll
                for (int i = 0; i < 4; ++i) {
                    int row = mb + wm * 64 + mt * 16 + quad * 4 + i;
                    int col = nb + wn * 64 + nt * 16 + l16;
                    Cf[(size_t)row * C_SZ + col] = acc[mt][nt][i];
                }
        return;
    }

    const int h = blockIdx.y * 2 + wn;   // head (wave-uniform)

    if (z == 2) {
        // V transpose-scatter to vt (B,H,D,T); 4 consecutive t per 8B store
        #pragma unroll
        for (int mt = 0; mt < 4; ++mt) {
            int gr0 = mb + wm * 64 + mt * 16 + quad * 4;
            int b = gr0 >> 11, t0 = gr0 & (T_SZ - 1);
            #pragma unroll
            for (int nt = 0; nt < 4; ++nt) {
                int d = nt * 16 + l16;
                uint2 pk;
                pk.x = cvt2(acc[mt][nt][0], acc[mt][nt][1]);
                pk.y = cvt2(acc[mt][nt][2], acc[mt][nt][3]);
                *(uint2*)&vt[((size_t)(b * NH + h) * HD + d) * T_SZ + t0] = pk;
            }
        }
        return;
    }

    // q/k: RoPE + RMSNorm, PERMUTED-D packed store (pos l16*4+j <=> d=j*16+l16)
    unsigned short* dst = (z == 0) ? qh : kh;
    const float qscale = (z == 0) ? (0.125f * 1.4426950408889634f) : 1.0f;
    const float eps = 1.1920929e-07f;

    #pragma unroll
    for (int mt = 0; mt < 4; ++mt) {
        #pragma unroll
        for (int i = 0; i < 4; ++i) {
            int gr = mb + wm * 64 + mt * 16 + quad * 4 + i;
            int b = gr >> 11, t = gr & (T_SZ - 1);
            float ce = cosp[t * 32 + l16];
            float se = sinp[t * 32 + l16];
            float co = cosp[t * 32 + 16 + l16];
            float so = sinp[t * 32 + 16 + l16];
            float a0 = acc[mt][0][i], a1 = acc[mt][1][i];
            float a2 = acc[mt][2][i], a3 = acc[mt][3][i];
            float y0 = a0 * ce + a2 * se;   // d = l16
            float y1 = a1 * co + a3 * so;   // d = 16+l16
            float y2 = a2 * ce - a0 * se;   // d = 32+l16
            float y3 = a3 * co - a1 * so;   // d = 48+l16
            float ss = y0 * y0 + y1 * y1 + y2 * y2 + y3 * y3;
            ss += __shfl_xor(ss, 1, 64);
            ss += __shfl_xor(ss, 2, 64);
            ss += __shfl_xor(ss, 4, 64);
            ss += __shfl_xor(ss, 8, 64);
            float rn = __builtin_amdgcn_rsqf(ss * (1.0f / 64.0f) + eps) * qscale;
            uint2 u;
            u.x = cvt2(y0 * rn, y1 * rn);
            u.y = cvt2(y2 * rn, y3 * rn);
            *(uint2*)&dst[((size_t)(b * NH + h) * T_SZ + t) * HD + l16 * 4] = u;
        }
    }
}

// ---------------------------------------------------------------------------
// Flash attention, S^T formulation. Block = 512 thr = 8 waves
// (2 key-halves wk x 4 q-quarters wq), 128-q tile of one (b,h), 64 keys/iter.
// Lockstep waves (1 barrier/iter), double-buffered K/V staging via
// global_load_lds (prefetch after barrier; vmcnt drain at NEXT barrier).
// q/k are in permuted-D layout (consistent on both sides -> dot invariant).
// Raw v_exp_f32 (args bounded by RMSNorm: |s| <= ~11.6 log2 units).
// ---------------------------------------------------------------------------
__global__ __launch_bounds__(512, 4)
void attn(const unsigned short* __restrict__ qh,
          const unsigned short* __restrict__ kh,
          const unsigned short* __restrict__ vt,
          unsigned short* __restrict__ yb)
{
    // [0,8192)x2: K bufs; [16384,24576)x2: V bufs; [32768,53248): Ps (8 waves
    // x 32 x 40); [53248,54272): lred. Epilogue Ored reuses [0,34816).
    __shared__ __align__(16) char smem[54272];

    const int tid = threadIdx.x;
    const int wave = tid >> 6, lane = tid & 63;
    const int wk = wave & 1, wq = wave >> 1;               // wq 0..3
    const int quad = lane >> 4, l16 = lane & 15;
    const int qb = blockIdx.x * 128;
    const int h = blockIdx.y, b = blockIdx.z;

    unsigned short* Ps = (unsigned short*)(smem + 32768) + wave * (32 * 40);
    float* lred = (float*)(smem + 53248);                  // [2][128]
    float* Ored = (float*)smem;

    const unsigned short* Qg = qh + ((size_t)(b * NH + h) * T_SZ + qb) * HD;
    const unsigned short* Kg = kh + (size_t)(b * NH + h) * T_SZ * HD;
    const unsigned short* Vg = vt + (size_t)(b * NH + h) * HD * T_SZ;

    // staging geometry: lane covers (row srow, chunk slot) of a 64x64 tile;
    // slot s of row r holds global chunk s^(r&7)
    const int srow = wave * 8 + (lane >> 3);     // 0..63
    const int sc   = ((lane & 7) ^ (srow & 7)) * 8;

    // prologue: stage tile 0 into buf 0
    gload_lds16(&Kg[(size_t)srow * HD + sc],
                (unsigned short*)(smem) + wave * 512);
    gload_lds16(&Vg[(size_t)srow * T_SZ + 0 + sc],
                (unsigned short*)(smem + 16384) + wave * 512);

    // Q B-frags: q row = wq*32 + n*16 + l16, k-chunk c*32 + quad*8 (permuted d)
    short8 qfr[2][2];
    #pragma unroll
    for (int n = 0; n < 2; ++n)
        #pragma unroll
        for (int c = 0; c < 2; ++c)
            qfr[n][c] = *(const short8*)&Qg[(size_t)(wq * 32 + n * 16 + l16) * HD + c * 32 + quad * 8];

    floatx4 o[4][2] = {};          // [nd (d tile)][nv (q tile)]
    float l_acc[2] = {0.f, 0.f};

    for (int it = 0; it < 32; ++it) {
        const int cur = it & 1;
        unsigned short* Ks = (unsigned short*)(smem + cur * 8192);
        unsigned short* Vs = (unsigned short*)(smem + 16384 + cur * 8192);

        __syncthreads();   // buf[cur] staged (vmcnt drained); buf[cur^1] free

        // prefetch next tile into the other buffer (wraps on last iter)
        {
            const int nst = ((it + 1) & 31) * 64;
            gload_lds16(&Kg[(size_t)(nst + srow) * HD + sc],
                        (unsigned short*)(smem + (cur ^ 1) * 8192) + wave * 512);
            gload_lds16(&Vg[(size_t)srow * T_SZ + nst + sc],
                        (unsigned short*)(smem + 16384 + (cur ^ 1) * 8192) + wave * 512);
        }

        // K A-frags: key rows r = wk*32 + kt*16 + l16, chunk cc*4+quad
        short8 af[2][2];
        #pragma unroll
        for (int kt = 0; kt < 2; ++kt) {
            int r = wk * 32 + kt * 16 + l16;
            #pragma unroll
            for (int cc = 0; cc < 2; ++cc)
                af[kt][cc] = *(const short8*)&Ks[r * 64 + (((cc * 4 + quad) ^ (r & 7)) * 8)];
        }
        // V A-frags: d rows r = nd*16 + l16, key chunk wk*4+quad
        short8 av[4];
        #pragma unroll
        for (int nd = 0; nd < 4; ++nd) {
            int r = nd * 16 + l16;
            av[nd] = *(const short8*)&Vs[r * 64 + (((wk * 4 + quad) ^ (r & 7)) * 8)];
        }

        // S^T: A = K rows (m=key), B = Q regs (n=q). D: col=l16=q, row=key
        floatx4 s[2][2];
        #pragma unroll
        for (int n = 0; n < 2; ++n) {
            floatx4 z0 = {0.f, 0.f, 0.f, 0.f};
            z0 = __builtin_amdgcn_mfma_f32_16x16x32_bf16(af[0][0], qfr[n][0], z0, 0, 0, 0);
            s[0][n] = __builtin_amdgcn_mfma_f32_16x16x32_bf16(af[0][1], qfr[n][1], z0, 0, 0, 0);
            floatx4 z1 = {0.f, 0.f, 0.f, 0.f};
            z1 = __builtin_amdgcn_mfma_f32_16x16x32_bf16(af[1][0], qfr[n][0], z1, 0, 0, 0);
            s[1][n] = __builtin_amdgcn_mfma_f32_16x16x32_bf16(af[1][1], qfr[n][1], z1, 0, 0, 0);
        }

        // p = exp2(s) raw v_exp_f32; per-lane l accum; packed cvt; Ps
        #pragma unroll
        for (int kt = 0; kt < 2; ++kt)
            #pragma unroll
            for (int n = 0; n < 2; ++n) {
                float p0 = __builtin_amdgcn_exp2f(s[kt][n][0]);
                float p1 = __builtin_amdgcn_exp2f(s[kt][n][1]);
                float p2 = __builtin_amdgcn_exp2f(s[kt][n][2]);
                float p3 = __builtin_amdgcn_exp2f(s[kt][n][3]);
                l_acc[n] += (p0 + p1) + (p2 + p3);
                uint2 pk;
                pk.x = cvt2(p0, p1);
                pk.y = cvt2(p2, p3);
                *(uint2*)&Ps[(n * 16 + l16) * 40 + kt * 16 + quad * 4] = pk;
            }

        // O^T += V^T x P^T  (wave-private Ps; b128 frag read; lgkmcnt RAW)
        #pragma unroll
        for (int nv = 0; nv < 2; ++nv) {
            short8 pf = *(const short8*)&Ps[(nv * 16 + l16) * 40 + quad * 8];
            #pragma unroll
            for (int nd = 0; nd < 4; ++nd)
                o[nd][nv] = __builtin_amdgcn_mfma_f32_16x16x32_bf16(av[nd], pf, o[nd][nv], 0, 0, 0);
        }
    }

    // l: reduce across quads (same l16 = same q)
    #pragma unroll
    for (int n = 0; n < 2; ++n) {
        l_acc[n] += __shfl_xor(l_acc[n], 16, 64);
        l_acc[n] += __shfl_xor(l_acc[n], 32, 64);
    }
    if (quad == 0) {
        #pragma unroll
        for (int n = 0; n < 2; ++n)
            lred[wk * 128 + wq * 32 + n * 16 + l16] = l_acc[n];
    }
    __syncthreads();   // loop LDS fully consumed before Ored overwrites

    if (wk == 1) {
        #pragma unroll
        for (int nv = 0; nv < 2; ++nv)
            #pragma unroll
            for (int nd = 0; nd < 4; ++nd)
                *(floatx4*)&Ored[(size_t)wq * (32 * 68) + (nv * 16 + l16) * 68 + nd * 16 + quad * 4] = o[nd][nv];
    }
    __syncthreads();

    if (wk == 0) {
        #pragma unroll
        for (int nv = 0; nv < 2; ++nv) {
            int qi = wq * 32 + nv * 16 + l16;
            float lt = lred[qi] + lred[128 + qi];
            float inv = 1.0f / lt;
            int t = qb + qi;
            #pragma unroll
            for (int nd = 0; nd < 4; ++nd) {
                floatx4 r = *(const floatx4*)&Ored[(size_t)wq * (32 * 68) + (nv * 16 + l16) * 68 + nd * 16 + quad * 4];
                floatx4 ov = o[nd][nv];
                uint2 u;
                u.x = cvt2((ov[0] + r[0]) * inv, (ov[1] + r[1]) * inv);
                u.y = cvt2((ov[2] + r[2]) * inv, (ov[3] + r[3]) * inv);
                *(uint2*)&yb[((size_t)b * T_SZ + t) * C_SZ + h * 64 + nd * 16 + quad * 4] = u;
            }
        }
    }
}

// ---------------------------------------------------------------------------
extern "C" void kernel_launch(void* const* d_in, const int* in_sizes, int n_in,
                              void* d_out, int out_size, void* d_ws, size_t ws_size,
                              hipStream_t stream)
{
    const float* x    = (const float*)d_in[0];
    const float* cosp = (const float*)d_in[1];
    const float* sinp = (const float*)d_in[2];
    const float* Wq   = (const float*)d_in[3];
    const float* Wk   = (const float*)d_in[4];
    const float* Wv   = (const float*)d_in[5];
    const float* Wo   = (const float*)d_in[6];
    float* out = (float*)d_out;

    // workspace (40 MB): xb/yb alias (xb dead after QKV GEMM)
    char* ws = (char*)d_ws;
    unsigned short* xb = (unsigned short*)(ws);               // 8 MB (B,T,C)
    unsigned short* yb = xb;                                  // alias after attn
    unsigned short* wb = (unsigned short*)(ws + (8u  << 20)); // 8 MB Wq,Wk,Wv,Wo
    unsigned short* qh = (unsigned short*)(ws + (16u << 20)); // 8 MB (B,H,T,D')
    unsigned short* kh = (unsigned short*)(ws + (24u << 20)); // 8 MB (B,H,T,D')
    unsigned short* vt = (unsigned short*)(ws + (32u << 20)); // 8 MB (B,H,D,T)

    cvtk<<<dim3(512, 5), 256, 0, stream>>>(x, Wq, Wk, Wv, Wo, xb, wb);
    gemm_nt<0><<<dim3(32, 8, 3), 256, 0, stream>>>(
        xb, wb, cosp, sinp, qh, kh, vt, nullptr);
    attn<<<dim3(16, NH, B_SZ), 512, 0, stream>>>(qh, kh, vt, yb);
    gemm_nt<1><<<dim3(32, 8, 1), 256, 0, stream>>>(
        yb, wb + (size_t)3 * C_SZ * C_SZ, nullptr, nullptr,
        nullptr, nullptr, nullptr, out);
}

// Round 11
// 189.852 us; speedup vs baseline: 1.0665x; 1.0665x over previous
//
#include <hip/hip_runtime.h>
#include <stdint.h>

typedef __attribute__((ext_vector_type(8))) short short8;
typedef __attribute__((ext_vector_type(4))) float floatx4;

#define B_SZ 2
#define T_SZ 2048
#define NH   16
#define HD   64
#define C_SZ 1024
#define M_SZ (B_SZ * T_SZ)   // 4096 tokens

// packed fp32x2 -> bf16x2 (RNE), gfx950 hardware instruction
static __device__ __forceinline__ unsigned int cvt2(float a, float b) {
    unsigned int r;
    asm("v_cvt_pk_bf16_f32 %0, %1, %2" : "=v"(r) : "v"(a), "v"(b));
    return r;
}

// async global->LDS, 16B per lane; LDS dest = wave-uniform base + lane*16
static __device__ __forceinline__ void gload_lds16(const void* g, void* l) {
    __builtin_amdgcn_global_load_lds(
        (const __attribute__((address_space(1))) void*)g,
        (__attribute__((address_space(3))) void*)l, 16, 0, 0);
}

// ---------------------------------------------------------------------------
// fp32 -> bf16 pre-convert (memory-bound): y=0 -> x, y=1..4 -> W's
// ---------------------------------------------------------------------------
__global__ __launch_bounds__(256)
void cvtk(const float* __restrict__ x,
          const float* __restrict__ w0, const float* __restrict__ w1,
          const float* __restrict__ w2, const float* __restrict__ w3,
          unsigned short* __restrict__ xb, unsigned short* __restrict__ wb)
{
    const float* src; unsigned short* dst; int n4;
    const int y = blockIdx.y;
    if (y == 0) { src = x; dst = xb; n4 = (M_SZ * C_SZ) / 4; }
    else {
        src = (y == 1 ? w0 : y == 2 ? w1 : y == 3 ? w2 : w3);
        dst = wb + (size_t)(y - 1) * C_SZ * C_SZ;
        n4 = (C_SZ * C_SZ) / 4;
    }
    for (int i = blockIdx.x * 256 + threadIdx.x; i < n4; i += gridDim.x * 256) {
        float4 f = *(const float4*)&src[(size_t)i * 4];
        uint2 u;
        u.x = cvt2(f.x, f.y);
        u.y = cvt2(f.z, f.w);
        *(uint2*)&dst[(size_t)i * 4] = u;
    }
}

// ---------------------------------------------------------------------------
// NT GEMM, all-bf16: C[m,n] = sum_k A[m,k]*W[n,k]  (N=K=1024)
// TM x 128 tile, BK=64 (16 K-steps), TWO barriers per iter (R9 structure:
// proven fastest — dbuf with smaller bodies regressed, R10 post-mortem).
// Staging via global_load_lds 16B into XOR-swizzled unpadded LDS (rows 128B,
// 8 chunk-slots; slot s of row r holds global chunk s^(r&7) -> 2-way banks).
// TM=128: waves 2x2, acc[4][4]. TM=64: waves 1x4 (all share M), acc[4][2].
// MODE 0 (QKV, TM=128): Wp = Wb + z*C*C; fused epilogues:
//   z=0/1: RoPE + RMSNorm (+0.125*log2e for q) -> qh/kh in PERMUTED-D layout
//          (pos l16*4+j holds d = j*16+l16 — QK-dot invariant, both sides).
//   z=2: transpose -> vt (B,H,D,T), true d.
// MODE 1 (out-proj, TM=64 for 512 blocks = 2/CU): writes fp32 (B,T,C) to Cf.
// ---------------------------------------------------------------------------
template <int MODE, int TM>
__global__ __launch_bounds__(256)
void gemm_nt(const unsigned short* __restrict__ A,
             const unsigned short* __restrict__ Wb,
             const float* __restrict__ cosp,
             const float* __restrict__ sinp,
             unsigned short* __restrict__ qh,
             unsigned short* __restrict__ kh,
             unsigned short* __restrict__ vt,
             float* __restrict__ Cf)
{
    constexpr int K = C_SZ;
    constexpr int NT = (TM == 128) ? 4 : 2;
    __shared__ __align__(16) unsigned short As[TM * 64];
    __shared__ __align__(16) unsigned short Bs[128 * 64];

    const int tid  = threadIdx.x;
    const int wave = tid >> 6, lane = tid & 63;
    const int quad = lane >> 4, l16 = lane & 15;
    const int mwo = (TM == 128) ? (wave >> 1) * 64 : 0;          // wave M offset
    const int nwo = (TM == 128) ? (wave & 1) * 64 : wave * 32;   // wave N offset
    const int mb = blockIdx.x * TM, nb = blockIdx.y * 128;
    const int z  = blockIdx.z;

    const unsigned short* Wp = (MODE == 0) ? (Wb + (size_t)z * C_SZ * C_SZ) : Wb;

    floatx4 acc[4][NT] = {};

    const int lrow = lane >> 3;   // 0..7
    const int lsw  = lane & 7;    // chunk slot

    for (int k0 = 0; k0 < K; k0 += 64) {
        __syncthreads();
        #pragma unroll
        for (int j = 0; j < TM / 32; ++j) {
            int rb = j * 32 + wave * 8;
            int r  = rb + lrow;
            int col = (lsw ^ (r & 7)) * 8;
            gload_lds16(&A[(size_t)(mb + r) * K + k0 + col], &As[rb * 64]);
        }
        #pragma unroll
        for (int j = 0; j < 4; ++j) {
            int rb = j * 32 + wave * 8;
            int r  = rb + lrow;
            int col = (lsw ^ (r & 7)) * 8;
            gload_lds16(&Wp[(size_t)(nb + r) * K + k0 + col], &Bs[rb * 64]);
        }
        __syncthreads();

        #pragma unroll
        for (int kk = 0; kk < 2; ++kk) {
            short8 af[4], bfr[NT];
            #pragma unroll
            for (int mt = 0; mt < 4; ++mt) {
                int r = mwo + mt * 16 + l16;
                af[mt] = *(const short8*)&As[r * 64 + (((kk * 4 + quad) ^ (r & 7)) * 8)];
            }
            #pragma unroll
            for (int nt = 0; nt < NT; ++nt) {
                int r = nwo + nt * 16 + l16;
                bfr[nt] = *(const short8*)&Bs[r * 64 + (((kk * 4 + quad) ^ (r & 7)) * 8)];
            }
            #pragma unroll
            for (int mt = 0; mt < 4; ++mt)
                #pragma unroll
                for (int nt = 0; nt < NT; ++nt)
                    acc[mt][nt] = __builtin_amdgcn_mfma_f32_16x16x32_bf16(
                        af[mt], bfr[nt], acc[mt][nt], 0, 0, 0);
        }
    }

    if (MODE == 1) {
        #pragma unroll
        for (int mt = 0; mt < 4; ++mt)
            #pragma unroll
            for (int nt = 0; nt < NT; ++nt)
                #pragma unroll
                for (int i = 0; i < 4; ++i) {
                    int row = mb + mwo + mt * 16 + quad * 4 + i;
                    int col = nb + nwo + nt * 16 + l16;
                    Cf[(size_t)row * C_SZ + col] = acc[mt][nt][i];
                }
        return;
    }

    const int h = blockIdx.y * 2 + (wave & 1);   // head (wave-uniform)

    if (z == 2) {
        // V transpose-scatter to vt (B,H,D,T); 4 consecutive t per 8B store
        #pragma unroll
        for (int mt = 0; mt < 4; ++mt) {
            int gr0 = mb + mwo + mt * 16 + quad * 4;
            int b = gr0 >> 11, t0 = gr0 & (T_SZ - 1);
            #pragma unroll
            for (int nt = 0; nt < 4; ++nt) {
                int d = nt * 16 + l16;
                uint2 pk;
                pk.x = cvt2(acc[mt][nt][0], acc[mt][nt][1]);
                pk.y = cvt2(acc[mt][nt][2], acc[mt][nt][3]);
                *(uint2*)&vt[((size_t)(b * NH + h) * HD + d) * T_SZ + t0] = pk;
            }
        }
        return;
    }

    // q/k: RoPE + RMSNorm, PERMUTED-D packed store (pos l16*4+j <=> d=j*16+l16)
    unsigned short* dst = (z == 0) ? qh : kh;
    const float qscale = (z == 0) ? (0.125f * 1.4426950408889634f) : 1.0f;
    const float eps = 1.1920929e-07f;

    #pragma unroll
    for (int mt = 0; mt < 4; ++mt) {
        #pragma unroll
        for (int i = 0; i < 4; ++i) {
            int gr = mb + mwo + mt * 16 + quad * 4 + i;
            int b = gr >> 11, t = gr & (T_SZ - 1);
            float ce = cosp[t * 32 + l16];
            float se = sinp[t * 32 + l16];
            float co = cosp[t * 32 + 16 + l16];
            float so = sinp[t * 32 + 16 + l16];
            float a0 = acc[mt][0][i], a1 = acc[mt][1][i];
            float a2 = acc[mt][2][i], a3 = acc[mt][3][i];
            float y0 = a0 * ce + a2 * se;   // d = l16
            float y1 = a1 * co + a3 * so;   // d = 16+l16
            float y2 = a2 * ce - a0 * se;   // d = 32+l16
            float y3 = a3 * co - a1 * so;   // d = 48+l16
            float ss = y0 * y0 + y1 * y1 + y2 * y2 + y3 * y3;
            ss += __shfl_xor(ss, 1, 64);
            ss += __shfl_xor(ss, 2, 64);
            ss += __shfl_xor(ss, 4, 64);
            ss += __shfl_xor(ss, 8, 64);
            float rn = __builtin_amdgcn_rsqf(ss * (1.0f / 64.0f) + eps) * qscale;
            uint2 u;
            u.x = cvt2(y0 * rn, y1 * rn);
            u.y = cvt2(y2 * rn, y3 * rn);
            *(uint2*)&dst[((size_t)(b * NH + h) * T_SZ + t) * HD + l16 * 4] = u;
        }
    }
}

// ---------------------------------------------------------------------------
// Flash attention, S^T formulation. Block = 512 thr = 8 waves
// (2 key-halves wk x 4 q-quarters wq), 128-q tile of one (b,h), 64 keys/iter.
// Lockstep waves (1 barrier/iter), double-buffered K/V staging via
// global_load_lds (prefetch after barrier; vmcnt drain at NEXT barrier).
// q/k are in permuted-D layout (consistent on both sides -> dot invariant).
// Raw v_exp_f32 (args bounded by RMSNorm: |s| <= ~11.6 log2 units).
// ---------------------------------------------------------------------------
__global__ __launch_bounds__(512, 4)
void attn(const unsigned short* __restrict__ qh,
          const unsigned short* __restrict__ kh,
          const unsigned short* __restrict__ vt,
          unsigned short* __restrict__ yb)
{
    // [0,8192)x2: K bufs; [16384,24576)x2: V bufs; [32768,53248): Ps (8 waves
    // x 32 x 40); [53248,54272): lred. Epilogue Ored reuses [0,34816).
    __shared__ __align__(16) char smem[54272];

    const int tid = threadIdx.x;
    const int wave = tid >> 6, lane = tid & 63;
    const int wk = wave & 1, wq = wave >> 1;               // wq 0..3
    const int quad = lane >> 4, l16 = lane & 15;
    const int qb = blockIdx.x * 128;
    const int h = blockIdx.y, b = blockIdx.z;

    unsigned short* Ps = (unsigned short*)(smem + 32768) + wave * (32 * 40);
    float* lred = (float*)(smem + 53248);                  // [2][128]
    float* Ored = (float*)smem;

    const unsigned short* Qg = qh + ((size_t)(b * NH + h) * T_SZ + qb) * HD;
    const unsigned short* Kg = kh + (size_t)(b * NH + h) * T_SZ * HD;
    const unsigned short* Vg = vt + (size_t)(b * NH + h) * HD * T_SZ;

    // staging geometry: lane covers (row srow, chunk slot) of a 64x64 tile;
    // slot s of row r holds global chunk s^(r&7)
    const int srow = wave * 8 + (lane >> 3);     // 0..63
    const int sc   = ((lane & 7) ^ (srow & 7)) * 8;

    // prologue: stage tile 0 into buf 0
    gload_lds16(&Kg[(size_t)srow * HD + sc],
                (unsigned short*)(smem) + wave * 512);
    gload_lds16(&Vg[(size_t)srow * T_SZ + 0 + sc],
                (unsigned short*)(smem + 16384) + wave * 512);

    // Q B-frags: q row = wq*32 + n*16 + l16, k-chunk c*32 + quad*8 (permuted d)
    short8 qfr[2][2];
    #pragma unroll
    for (int n = 0; n < 2; ++n)
        #pragma unroll
        for (int c = 0; c < 2; ++c)
            qfr[n][c] = *(const short8*)&Qg[(size_t)(wq * 32 + n * 16 + l16) * HD + c * 32 + quad * 8];

    floatx4 o[4][2] = {};          // [nd (d tile)][nv (q tile)]
    float l_acc[2] = {0.f, 0.f};

    for (int it = 0; it < 32; ++it) {
        const int cur = it & 1;
        unsigned short* Ks = (unsigned short*)(smem + cur * 8192);
        unsigned short* Vs = (unsigned short*)(smem + 16384 + cur * 8192);

        __syncthreads();   // buf[cur] staged (vmcnt drained); buf[cur^1] free

        // prefetch next tile into the other buffer (wraps on last iter)
        {
            const int nst = ((it + 1) & 31) * 64;
            gload_lds16(&Kg[(size_t)(nst + srow) * HD + sc],
                        (unsigned short*)(smem + (cur ^ 1) * 8192) + wave * 512);
            gload_lds16(&Vg[(size_t)srow * T_SZ + nst + sc],
                        (unsigned short*)(smem + 16384 + (cur ^ 1) * 8192) + wave * 512);
        }

        // K A-frags: key rows r = wk*32 + kt*16 + l16, chunk cc*4+quad
        short8 af[2][2];
        #pragma unroll
        for (int kt = 0; kt < 2; ++kt) {
            int r = wk * 32 + kt * 16 + l16;
            #pragma unroll
            for (int cc = 0; cc < 2; ++cc)
                af[kt][cc] = *(const short8*)&Ks[r * 64 + (((cc * 4 + quad) ^ (r & 7)) * 8)];
        }
        // V A-frags: d rows r = nd*16 + l16, key chunk wk*4+quad
        short8 av[4];
        #pragma unroll
        for (int nd = 0; nd < 4; ++nd) {
            int r = nd * 16 + l16;
            av[nd] = *(const short8*)&Vs[r * 64 + (((wk * 4 + quad) ^ (r & 7)) * 8)];
        }

        // S^T: A = K rows (m=key), B = Q regs (n=q). D: col=l16=q, row=key
        floatx4 s[2][2];
        #pragma unroll
        for (int n = 0; n < 2; ++n) {
            floatx4 z0 = {0.f, 0.f, 0.f, 0.f};
            z0 = __builtin_amdgcn_mfma_f32_16x16x32_bf16(af[0][0], qfr[n][0], z0, 0, 0, 0);
            s[0][n] = __builtin_amdgcn_mfma_f32_16x16x32_bf16(af[0][1], qfr[n][1], z0, 0, 0, 0);
            floatx4 z1 = {0.f, 0.f, 0.f, 0.f};
            z1 = __builtin_amdgcn_mfma_f32_16x16x32_bf16(af[1][0], qfr[n][0], z1, 0, 0, 0);
            s[1][n] = __builtin_amdgcn_mfma_f32_16x16x32_bf16(af[1][1], qfr[n][1], z1, 0, 0, 0);
        }

        // p = exp2(s) raw v_exp_f32; per-lane l accum; packed cvt; Ps
        #pragma unroll
        for (int kt = 0; kt < 2; ++kt)
            #pragma unroll
            for (int n = 0; n < 2; ++n) {
                float p0 = __builtin_amdgcn_exp2f(s[kt][n][0]);
                float p1 = __builtin_amdgcn_exp2f(s[kt][n][1]);
                float p2 = __builtin_amdgcn_exp2f(s[kt][n][2]);
                float p3 = __builtin_amdgcn_exp2f(s[kt][n][3]);
                l_acc[n] += (p0 + p1) + (p2 + p3);
                uint2 pk;
                pk.x = cvt2(p0, p1);
                pk.y = cvt2(p2, p3);
                *(uint2*)&Ps[(n * 16 + l16) * 40 + kt * 16 + quad * 4] = pk;
            }

        // O^T += V^T x P^T  (wave-private Ps; b128 frag read; lgkmcnt RAW)
        #pragma unroll
        for (int nv = 0; nv < 2; ++nv) {
            short8 pf = *(const short8*)&Ps[(nv * 16 + l16) * 40 + quad * 8];
            #pragma unroll
            for (int nd = 0; nd < 4; ++nd)
                o[nd][nv] = __builtin_amdgcn_mfma_f32_16x16x32_bf16(av[nd], pf, o[nd][nv], 0, 0, 0);
        }
    }

    // l: reduce across quads (same l16 = same q)
    #pragma unroll
    for (int n = 0; n < 2; ++n) {
        l_acc[n] += __shfl_xor(l_acc[n], 16, 64);
        l_acc[n] += __shfl_xor(l_acc[n], 32, 64);
    }
    if (quad == 0) {
        #pragma unroll
        for (int n = 0; n < 2; ++n)
            lred[wk * 128 + wq * 32 + n * 16 + l16] = l_acc[n];
    }
    __syncthreads();   // loop LDS fully consumed before Ored overwrites

    if (wk == 1) {
        #pragma unroll
        for (int nv = 0; nv < 2; ++nv)
            #pragma unroll
            for (int nd = 0; nd < 4; ++nd)
                *(floatx4*)&Ored[(size_t)wq * (32 * 68) + (nv * 16 + l16) * 68 + nd * 16 + quad * 4] = o[nd][nv];
    }
    __syncthreads();

    if (wk == 0) {
        #pragma unroll
        for (int nv = 0; nv < 2; ++nv) {
            int qi = wq * 32 + nv * 16 + l16;
            float lt = lred[qi] + lred[128 + qi];
            float inv = 1.0f / lt;
            int t = qb + qi;
            #pragma unroll
            for (int nd = 0; nd < 4; ++nd) {
                floatx4 r = *(const floatx4*)&Ored[(size_t)wq * (32 * 68) + (nv * 16 + l16) * 68 + nd * 16 + quad * 4];
                floatx4 ov = o[nd][nv];
                uint2 u;
                u.x = cvt2((ov[0] + r[0]) * inv, (ov[1] + r[1]) * inv);
                u.y = cvt2((ov[2] + r[2]) * inv, (ov[3] + r[3]) * inv);
                *(uint2*)&yb[((size_t)b * T_SZ + t) * C_SZ + h * 64 + nd * 16 + quad * 4] = u;
            }
        }
    }
}

// ---------------------------------------------------------------------------
extern "C" void kernel_launch(void* const* d_in, const int* in_sizes, int n_in,
                              void* d_out, int out_size, void* d_ws, size_t ws_size,
                              hipStream_t stream)
{
    const float* x    = (const float*)d_in[0];
    const float* cosp = (const float*)d_in[1];
    const float* sinp = (const float*)d_in[2];
    const float* Wq   = (const float*)d_in[3];
    const float* Wk   = (const float*)d_in[4];
    const float* Wv   = (const float*)d_in[5];
    const float* Wo   = (const float*)d_in[6];
    float* out = (float*)d_out;

    // workspace (40 MB): xb/yb alias (xb dead after QKV GEMM)
    char* ws = (char*)d_ws;
    unsigned short* xb = (unsigned short*)(ws);               // 8 MB (B,T,C)
    unsigned short* yb = xb;                                  // alias after attn
    unsigned short* wb = (unsigned short*)(ws + (8u  << 20)); // 8 MB Wq,Wk,Wv,Wo
    unsigned short* qh = (unsigned short*)(ws + (16u << 20)); // 8 MB (B,H,T,D')
    unsigned short* kh = (unsigned short*)(ws + (24u << 20)); // 8 MB (B,H,T,D')
    unsigned short* vt = (unsigned short*)(ws + (32u << 20)); // 8 MB (B,H,D,T)

    cvtk<<<dim3(512, 5), 256, 0, stream>>>(x, Wq, Wk, Wv, Wo, xb, wb);
    gemm_nt<0, 128><<<dim3(32, 8, 3), 256, 0, stream>>>(
        xb, wb, cosp, sinp, qh, kh, vt, nullptr);
    attn<<<dim3(16, NH, B_SZ), 512, 0, stream>>>(qh, kh, vt, yb);
    gemm_nt<1, 64><<<dim3(64, 8, 1), 256, 0, stream>>>(
        yb, wb + (size_t)3 * C_SZ * C_SZ, nullptr, nullptr,
        nullptr, nullptr, nullptr, out);
}

// Round 12
// 181.266 us; speedup vs baseline: 1.1171x; 1.0474x over previous
//
#include <hip/hip_runtime.h>
#include <stdint.h>

typedef __attribute__((ext_vector_type(8))) short short8;
typedef __attribute__((ext_vector_type(4))) float floatx4;

#define B_SZ 2
#define T_SZ 2048
#define NH   16
#define HD   64
#define C_SZ 1024
#define M_SZ (B_SZ * T_SZ)   // 4096 tokens

// packed fp32x2 -> bf16x2 (RNE), gfx950 hardware instruction
static __device__ __forceinline__ unsigned int cvt2(float a, float b) {
    unsigned int r;
    asm("v_cvt_pk_bf16_f32 %0, %1, %2" : "=v"(r) : "v"(a), "v"(b));
    return r;
}

// async global->LDS, 16B per lane; LDS dest = wave-uniform base + lane*16
static __device__ __forceinline__ void gload_lds16(const void* g, void* l) {
    __builtin_amdgcn_global_load_lds(
        (const __attribute__((address_space(1))) void*)g,
        (__attribute__((address_space(3))) void*)l, 16, 0, 0);
}

// ---------------------------------------------------------------------------
// fp32 -> bf16 pre-convert (memory-bound): y=0 -> x, y=1..4 -> W's
// ---------------------------------------------------------------------------
__global__ __launch_bounds__(256)
void cvtk(const float* __restrict__ x,
          const float* __restrict__ w0, const float* __restrict__ w1,
          const float* __restrict__ w2, const float* __restrict__ w3,
          unsigned short* __restrict__ xb, unsigned short* __restrict__ wb)
{
    const float* src; unsigned short* dst; int n4;
    const int y = blockIdx.y;
    if (y == 0) { src = x; dst = xb; n4 = (M_SZ * C_SZ) / 4; }
    else {
        src = (y == 1 ? w0 : y == 2 ? w1 : y == 3 ? w2 : w3);
        dst = wb + (size_t)(y - 1) * C_SZ * C_SZ;
        n4 = (C_SZ * C_SZ) / 4;
    }
    for (int i = blockIdx.x * 256 + threadIdx.x; i < n4; i += gridDim.x * 256) {
        float4 f = *(const float4*)&src[(size_t)i * 4];
        uint2 u;
        u.x = cvt2(f.x, f.y);
        u.y = cvt2(f.z, f.w);
        *(uint2*)&dst[(size_t)i * 4] = u;
    }
}

// ---------------------------------------------------------------------------
// NT GEMM, all-bf16: C[m,n] = sum_k A[m,k]*W[n,k]  (K=1024)
// TM x TN tile, BK=64 (16 K-steps), two barriers/iter (R9 structure).
// Staging via global_load_lds 16B into XOR-swizzled unpadded LDS (rows 128B,
// 8 chunk-slots; slot s of row r holds global chunk s^(r&7) -> 2-way banks).
// Wave layouts: (128,64): 4x1 waves of 32x64 (NT=4 -> RoPE epilogue works,
// one head per block). (64,64): 2x2 waves of 32x32.
// MODE 0 (QKV, 128x64): Wp = Wb + z*C*C; fused epilogues:
//   z=0/1: RoPE + RMSNorm (+0.125*log2e for q) -> qh/kh in PERMUTED-D layout
//          (pos l16*4+j holds d = j*16+l16 — QK-dot invariant, both sides).
//   z=2: transpose -> vt (B,H,D,T), true d.
// MODE 1 (out-proj, 64x64): writes fp32 (B,T,C) to Cf.
// ---------------------------------------------------------------------------
template <int MODE, int TM, int TN>
__global__ __launch_bounds__(256)
void gemm_nt(const unsigned short* __restrict__ A,
             const unsigned short* __restrict__ Wb,
             const float* __restrict__ cosp,
             const float* __restrict__ sinp,
             unsigned short* __restrict__ qh,
             unsigned short* __restrict__ kh,
             unsigned short* __restrict__ vt,
             float* __restrict__ Cf)
{
    constexpr int K = C_SZ;
    constexpr int WVM = (TM == 128) ? 4 : 2;   // waves along m
    constexpr int WVN = 4 / WVM;               // waves along n
    constexpr int MT = TM / (16 * WVM);        // m-tiles of 16 per wave
    constexpr int NT = TN / (16 * WVN);        // n-tiles of 16 per wave
    __shared__ __align__(16) unsigned short As[TM * 64];
    __shared__ __align__(16) unsigned short Bs[TN * 64];

    const int tid  = threadIdx.x;
    const int wave = tid >> 6, lane = tid & 63;
    const int quad = lane >> 4, l16 = lane & 15;
    const int mwo = (wave / WVN) * (TM / WVM);
    const int nwo = (wave % WVN) * (TN / WVN);
    const int mb = blockIdx.x * TM, nb = blockIdx.y * TN;
    const int z  = blockIdx.z;

    const unsigned short* Wp = (MODE == 0) ? (Wb + (size_t)z * C_SZ * C_SZ) : Wb;

    floatx4 acc[MT][NT] = {};

    const int lrow = lane >> 3;   // 0..7
    const int lsw  = lane & 7;    // chunk slot

    for (int k0 = 0; k0 < K; k0 += 64) {
        __syncthreads();
        #pragma unroll
        for (int j = 0; j < TM / 32; ++j) {
            int rb = j * 32 + wave * 8;
            int r  = rb + lrow;
            int col = (lsw ^ (r & 7)) * 8;
            gload_lds16(&A[(size_t)(mb + r) * K + k0 + col], &As[rb * 64]);
        }
        #pragma unroll
        for (int j = 0; j < TN / 32; ++j) {
            int rb = j * 32 + wave * 8;
            int r  = rb + lrow;
            int col = (lsw ^ (r & 7)) * 8;
            gload_lds16(&Wp[(size_t)(nb + r) * K + k0 + col], &Bs[rb * 64]);
        }
        __syncthreads();

        #pragma unroll
        for (int kk = 0; kk < 2; ++kk) {
            short8 af[MT], bfr[NT];
            #pragma unroll
            for (int mt = 0; mt < MT; ++mt) {
                int r = mwo + mt * 16 + l16;
                af[mt] = *(const short8*)&As[r * 64 + (((kk * 4 + quad) ^ (r & 7)) * 8)];
            }
            #pragma unroll
            for (int nt = 0; nt < NT; ++nt) {
                int r = nwo + nt * 16 + l16;
                bfr[nt] = *(const short8*)&Bs[r * 64 + (((kk * 4 + quad) ^ (r & 7)) * 8)];
            }
            #pragma unroll
            for (int mt = 0; mt < MT; ++mt)
                #pragma unroll
                for (int nt = 0; nt < NT; ++nt)
                    acc[mt][nt] = __builtin_amdgcn_mfma_f32_16x16x32_bf16(
                        af[mt], bfr[nt], acc[mt][nt], 0, 0, 0);
        }
    }

    if (MODE == 1) {
        #pragma unroll
        for (int mt = 0; mt < MT; ++mt)
            #pragma unroll
            for (int nt = 0; nt < NT; ++nt)
                #pragma unroll
                for (int i = 0; i < 4; ++i) {
                    int row = mb + mwo + mt * 16 + quad * 4 + i;
                    int col = nb + nwo + nt * 16 + l16;
                    Cf[(size_t)row * C_SZ + col] = acc[mt][nt][i];
                }
        return;
    }

    const int h = blockIdx.y;   // one head per block (TN=64)

    if (z == 2) {
        // V transpose-scatter to vt (B,H,D,T); 4 consecutive t per 8B store
        #pragma unroll
        for (int mt = 0; mt < MT; ++mt) {
            int gr0 = mb + mwo + mt * 16 + quad * 4;
            int b = gr0 >> 11, t0 = gr0 & (T_SZ - 1);
            #pragma unroll
            for (int nt = 0; nt < 4; ++nt) {
                int d = nt * 16 + l16;
                uint2 pk;
                pk.x = cvt2(acc[mt][nt][0], acc[mt][nt][1]);
                pk.y = cvt2(acc[mt][nt][2], acc[mt][nt][3]);
                *(uint2*)&vt[((size_t)(b * NH + h) * HD + d) * T_SZ + t0] = pk;
            }
        }
        return;
    }

    // q/k: RoPE + RMSNorm, PERMUTED-D packed store (pos l16*4+j <=> d=j*16+l16)
    unsigned short* dst = (z == 0) ? qh : kh;
    const float qscale = (z == 0) ? (0.125f * 1.4426950408889634f) : 1.0f;
    const float eps = 1.1920929e-07f;

    #pragma unroll
    for (int mt = 0; mt < MT; ++mt) {
        #pragma unroll
        for (int i = 0; i < 4; ++i) {
            int gr = mb + mwo + mt * 16 + quad * 4 + i;
            int b = gr >> 11, t = gr & (T_SZ - 1);
            float ce = cosp[t * 32 + l16];
            float se = sinp[t * 32 + l16];
            float co = cosp[t * 32 + 16 + l16];
            float so = sinp[t * 32 + 16 + l16];
            float a0 = acc[mt][0][i], a1 = acc[mt][1][i];
            float a2 = acc[mt][2][i], a3 = acc[mt][3][i];
            float y0 = a0 * ce + a2 * se;   // d = l16
            float y1 = a1 * co + a3 * so;   // d = 16+l16
            float y2 = a2 * ce - a0 * se;   // d = 32+l16
            float y3 = a3 * co - a1 * so;   // d = 48+l16
            float ss = y0 * y0 + y1 * y1 + y2 * y2 + y3 * y3;
            ss += __shfl_xor(ss, 1, 64);
            ss += __shfl_xor(ss, 2, 64);
            ss += __shfl_xor(ss, 4, 64);
            ss += __shfl_xor(ss, 8, 64);
            float rn = __builtin_amdgcn_rsqf(ss * (1.0f / 64.0f) + eps) * qscale;
            uint2 u;
            u.x = cvt2(y0 * rn, y1 * rn);
            u.y = cvt2(y2 * rn, y3 * rn);
            *(uint2*)&dst[((size_t)(b * NH + h) * T_SZ + t) * HD + l16 * 4] = u;
        }
    }
}

// ---------------------------------------------------------------------------
// Flash attention, S^T formulation. Block = 512 thr = 8 waves
// (2 key-halves wk x 4 q-quarters wq), 128-q tile of one (b,h), 64 keys/iter.
// Lockstep waves (1 barrier/iter), double-buffered K/V staging via
// global_load_lds (prefetch after barrier; vmcnt drain at NEXT barrier).
// q/k are in permuted-D layout (consistent on both sides -> dot invariant).
// Raw v_exp_f32 (args bounded by RMSNorm: |s| <= ~11.6 log2 units).
// ---------------------------------------------------------------------------
__global__ __launch_bounds__(512, 4)
void attn(const unsigned short* __restrict__ qh,
          const unsigned short* __restrict__ kh,
          const unsigned short* __restrict__ vt,
          unsigned short* __restrict__ yb)
{
    // [0,8192)x2: K bufs; [16384,24576)x2: V bufs; [32768,53248): Ps (8 waves
    // x 32 x 40); [53248,54272): lred. Epilogue Ored reuses [0,34816).
    __shared__ __align__(16) char smem[54272];

    const int tid = threadIdx.x;
    const int wave = tid >> 6, lane = tid & 63;
    const int wk = wave & 1, wq = wave >> 1;               // wq 0..3
    const int quad = lane >> 4, l16 = lane & 15;
    const int qb = blockIdx.x * 128;
    const int h = blockIdx.y, b = blockIdx.z;

    unsigned short* Ps = (unsigned short*)(smem + 32768) + wave * (32 * 40);
    float* lred = (float*)(smem + 53248);                  // [2][128]
    float* Ored = (float*)smem;

    const unsigned short* Qg = qh + ((size_t)(b * NH + h) * T_SZ + qb) * HD;
    const unsigned short* Kg = kh + (size_t)(b * NH + h) * T_SZ * HD;
    const unsigned short* Vg = vt + (size_t)(b * NH + h) * HD * T_SZ;

    // staging geometry: lane covers (row srow, chunk slot) of a 64x64 tile;
    // slot s of row r holds global chunk s^(r&7)
    const int srow = wave * 8 + (lane >> 3);     // 0..63
    const int sc   = ((lane & 7) ^ (srow & 7)) * 8;

    // prologue: stage tile 0 into buf 0
    gload_lds16(&Kg[(size_t)srow * HD + sc],
                (unsigned short*)(smem) + wave * 512);
    gload_lds16(&Vg[(size_t)srow * T_SZ + 0 + sc],
                (unsigned short*)(smem + 16384) + wave * 512);

    // Q B-frags: q row = wq*32 + n*16 + l16, k-chunk c*32 + quad*8 (permuted d)
    short8 qfr[2][2];
    #pragma unroll
    for (int n = 0; n < 2; ++n)
        #pragma unroll
        for (int c = 0; c < 2; ++c)
            qfr[n][c] = *(const short8*)&Qg[(size_t)(wq * 32 + n * 16 + l16) * HD + c * 32 + quad * 8];

    floatx4 o[4][2] = {};          // [nd (d tile)][nv (q tile)]
    float l_acc[2] = {0.f, 0.f};

    for (int it = 0; it < 32; ++it) {
        const int cur = it & 1;
        unsigned short* Ks = (unsigned short*)(smem + cur * 8192);
        unsigned short* Vs = (unsigned short*)(smem + 16384 + cur * 8192);

        __syncthreads();   // buf[cur] staged (vmcnt drained); buf[cur^1] free

        // prefetch next tile into the other buffer (wraps on last iter)
        {
            const int nst = ((it + 1) & 31) * 64;
            gload_lds16(&Kg[(size_t)(nst + srow) * HD + sc],
                        (unsigned short*)(smem + (cur ^ 1) * 8192) + wave * 512);
            gload_lds16(&Vg[(size_t)srow * T_SZ + nst + sc],
                        (unsigned short*)(smem + 16384 + (cur ^ 1) * 8192) + wave * 512);
        }

        // K A-frags: key rows r = wk*32 + kt*16 + l16, chunk cc*4+quad
        short8 af[2][2];
        #pragma unroll
        for (int kt = 0; kt < 2; ++kt) {
            int r = wk * 32 + kt * 16 + l16;
            #pragma unroll
            for (int cc = 0; cc < 2; ++cc)
                af[kt][cc] = *(const short8*)&Ks[r * 64 + (((cc * 4 + quad) ^ (r & 7)) * 8)];
        }
        // V A-frags: d rows r = nd*16 + l16, key chunk wk*4+quad
        short8 av[4];
        #pragma unroll
        for (int nd = 0; nd < 4; ++nd) {
            int r = nd * 16 + l16;
            av[nd] = *(const short8*)&Vs[r * 64 + (((wk * 4 + quad) ^ (r & 7)) * 8)];
        }

        // S^T: A = K rows (m=key), B = Q regs (n=q). D: col=l16=q, row=key
        floatx4 s[2][2];
        #pragma unroll
        for (int n = 0; n < 2; ++n) {
            floatx4 z0 = {0.f, 0.f, 0.f, 0.f};
            z0 = __builtin_amdgcn_mfma_f32_16x16x32_bf16(af[0][0], qfr[n][0], z0, 0, 0, 0);
            s[0][n] = __builtin_amdgcn_mfma_f32_16x16x32_bf16(af[0][1], qfr[n][1], z0, 0, 0, 0);
            floatx4 z1 = {0.f, 0.f, 0.f, 0.f};
            z1 = __builtin_amdgcn_mfma_f32_16x16x32_bf16(af[1][0], qfr[n][0], z1, 0, 0, 0);
            s[1][n] = __builtin_amdgcn_mfma_f32_16x16x32_bf16(af[1][1], qfr[n][1], z1, 0, 0, 0);
        }

        // p = exp2(s) raw v_exp_f32; per-lane l accum; packed cvt; Ps
        #pragma unroll
        for (int kt = 0; kt < 2; ++kt)
            #pragma unroll
            for (int n = 0; n < 2; ++n) {
                float p0 = __builtin_amdgcn_exp2f(s[kt][n][0]);
                float p1 = __builtin_amdgcn_exp2f(s[kt][n][1]);
                float p2 = __builtin_amdgcn_exp2f(s[kt][n][2]);
                float p3 = __builtin_amdgcn_exp2f(s[kt][n][3]);
                l_acc[n] += (p0 + p1) + (p2 + p3);
                uint2 pk;
                pk.x = cvt2(p0, p1);
                pk.y = cvt2(p2, p3);
                *(uint2*)&Ps[(n * 16 + l16) * 40 + kt * 16 + quad * 4] = pk;
            }

        // O^T += V^T x P^T  (wave-private Ps; b128 frag read; lgkmcnt RAW)
        #pragma unroll
        for (int nv = 0; nv < 2; ++nv) {
            short8 pf = *(const short8*)&Ps[(nv * 16 + l16) * 40 + quad * 8];
            #pragma unroll
            for (int nd = 0; nd < 4; ++nd)
                o[nd][nv] = __builtin_amdgcn_mfma_f32_16x16x32_bf16(av[nd], pf, o[nd][nv], 0, 0, 0);
        }
    }

    // l: reduce across quads (same l16 = same q)
    #pragma unroll
    for (int n = 0; n < 2; ++n) {
        l_acc[n] += __shfl_xor(l_acc[n], 16, 64);
        l_acc[n] += __shfl_xor(l_acc[n], 32, 64);
    }
    if (quad == 0) {
        #pragma unroll
        for (int n = 0; n < 2; ++n)
            lred[wk * 128 + wq * 32 + n * 16 + l16] = l_acc[n];
    }
    __syncthreads();   // loop LDS fully consumed before Ored overwrites

    if (wk == 1) {
        #pragma unroll
        for (int nv = 0; nv < 2; ++nv)
            #pragma unroll
            for (int nd = 0; nd < 4; ++nd)
                *(floatx4*)&Ored[(size_t)wq * (32 * 68) + (nv * 16 + l16) * 68 + nd * 16 + quad * 4] = o[nd][nv];
    }
    __syncthreads();

    if (wk == 0) {
        #pragma unroll
        for (int nv = 0; nv < 2; ++nv) {
            int qi = wq * 32 + nv * 16 + l16;
            float lt = lred[qi] + lred[128 + qi];
            float inv = 1.0f / lt;
            int t = qb + qi;
            #pragma unroll
            for (int nd = 0; nd < 4; ++nd) {
                floatx4 r = *(const floatx4*)&Ored[(size_t)wq * (32 * 68) + (nv * 16 + l16) * 68 + nd * 16 + quad * 4];
                floatx4 ov = o[nd][nv];
                uint2 u;
                u.x = cvt2((ov[0] + r[0]) * inv, (ov[1] + r[1]) * inv);
                u.y = cvt2((ov[2] + r[2]) * inv, (ov[3] + r[3]) * inv);
                *(uint2*)&yb[((size_t)b * T_SZ + t) * C_SZ + h * 64 + nd * 16 + quad * 4] = u;
            }
        }
    }
}

// ---------------------------------------------------------------------------
extern "C" void kernel_launch(void* const* d_in, const int* in_sizes, int n_in,
                              void* d_out, int out_size, void* d_ws, size_t ws_size,
                              hipStream_t stream)
{
    const float* x    = (const float*)d_in[0];
    const float* cosp = (const float*)d_in[1];
    const float* sinp = (const float*)d_in[2];
    const float* Wq   = (const float*)d_in[3];
    const float* Wk   = (const float*)d_in[4];
    const float* Wv   = (const float*)d_in[5];
    const float* Wo   = (const float*)d_in[6];
    float* out = (float*)d_out;

    // workspace (40 MB): xb/yb alias (xb dead after QKV GEMM)
    char* ws = (char*)d_ws;
    unsigned short* xb = (unsigned short*)(ws);               // 8 MB (B,T,C)
    unsigned short* yb = xb;                                  // alias after attn
    unsigned short* wb = (unsigned short*)(ws + (8u  << 20)); // 8 MB Wq,Wk,Wv,Wo
    unsigned short* qh = (unsigned short*)(ws + (16u << 20)); // 8 MB (B,H,T,D')
    unsigned short* kh = (unsigned short*)(ws + (24u << 20)); // 8 MB (B,H,T,D')
    unsigned short* vt = (unsigned short*)(ws + (32u << 20)); // 8 MB (B,H,D,T)

    cvtk<<<dim3(512, 5), 256, 0, stream>>>(x, Wq, Wk, Wv, Wo, xb, wb);
    gemm_nt<0, 128, 64><<<dim3(32, 16, 3), 256, 0, stream>>>(
        xb, wb, cosp, sinp, qh, kh, vt, nullptr);
    attn<<<dim3(16, NH, B_SZ), 512, 0, stream>>>(qh, kh, vt, yb);
    gemm_nt<1, 64, 64><<<dim3(64, 16, 1), 256, 0, stream>>>(
        yb, wb + (size_t)3 * C_SZ * C_SZ, nullptr, nullptr,
        nullptr, nullptr, nullptr, out);
}